// Round 1
// baseline (332.596 us; speedup 1.0000x reference)
//
#include <hip/hip_runtime.h>
#include <math.h>

#define NN 512   // nodes
#define DD 64    // output feature dim
// ws layout (float offsets)
#define OFF_SXL 0u
#define OFF_SXR 524288u
#define OFF_XLR 1048576u
#define OFF_UU  1572864u
#define OFF_VV  1581056u
#define OFF_H1  1589248u
#define OFF_H2  2113536u
#define OFF_SA  2637824u

// ---------------- GEMM + preprocessing: xl, xr, scaled arrays, u, v ----------------
template<int K>
__global__ __launch_bounds__(256) void kpre(
    const float* __restrict__ src, int srcPerInst,
    const float* __restrict__ Wl0, const float* __restrict__ Wr0, const float* __restrict__ a0,
    const float* __restrict__ Wl1, const float* __restrict__ Wr1, const float* __restrict__ a1,
    float* __restrict__ ws)
{
    __shared__ float xs[32 * K];
    const int rb   = blockIdx.x;   // 0..15 row-block of 32
    const int inst = blockIdx.y;   // 0..15  (br*8 + batch)
    const int br   = inst >> 3;
    const int tid  = threadIdx.x;
    const float* Wl = br ? Wl1 : Wl0;
    const float* Wr = br ? Wr1 : Wr0;
    const float* av = br ? a1  : a0;
    const float* sp = src + (size_t)(srcPerInst ? inst : (inst & 7)) * NN * K + (size_t)rb * 32 * K;

    {   // stage 32 rows x K floats (contiguous)
        const float4* s4 = (const float4*)sp;
        float4* d4 = (float4*)xs;
        const int tot = 32 * K / 4;
        for (int idx = tid; idx < tot; idx += 256) d4[idx] = s4[idx];
    }
    __syncthreads();

    const int d = tid & 63, ig = tid >> 6;
    float accl[8], accr[8];
#pragma unroll
    for (int i = 0; i < 8; ++i) { accl[i] = 0.f; accr[i] = 0.f; }
    for (int k = 0; k < K; ++k) {
        float wl = Wl[k * 64 + d], wr = Wr[k * 64 + d];
#pragma unroll
        for (int i = 0; i < 8; ++i) {
            float xv = xs[(ig * 8 + i) * K + k];   // wave-uniform broadcast
            accl[i] = fmaf(xv, wl, accl[i]);
            accr[i] = fmaf(xv, wr, accr[i]);
        }
    }
    float aval = av[d];
    float absa = fabsf(aval);
    float* SXL = ws + OFF_SXL;
    float* SXR = ws + OFF_SXR;
    float* XLR = ws + OFF_XLR;
    float* UU  = ws + OFF_UU;
    float* VV  = ws + OFF_VV;
    float* SA  = ws + OFF_SA;
#pragma unroll
    for (int i = 0; i < 8; ++i) {
        int row = rb * 32 + ig * 8 + i;
        size_t o = (size_t)(inst * NN + row) * 64 + d;
        XLR[o] = accl[i];
        SXL[o] = absa * accl[i];
        SXR[o] = absa * accr[i];
        float pu = aval * accr[i];   // -> u_i (query side, from xr)
        float pv = aval * accl[i];   // -> v_j (source side, from xl)
#pragma unroll
        for (int mm = 32; mm > 0; mm >>= 1) {
            pu += __shfl_xor(pu, mm, 64);
            pv += __shfl_xor(pv, mm, 64);
        }
        if (d == 0) { UU[inst * NN + row] = 0.6f * pu; VV[inst * NN + row] = 0.6f * pv; }
    }
    if (rb == 0 && ig == 0 && (inst & 7) == 0) SA[br * 64 + d] = (aval >= 0.f) ? 0.4f : -0.4f;
}

// ---------------- fused attention: scores + online softmax + PV + bias + tanh ----------------
__global__ __launch_bounds__(256) void kattn(
    const float* __restrict__ ws,
    const float* __restrict__ b0, const float* __restrict__ b1,
    float* __restrict__ Hout)
{
    __shared__ float xt[64 * 64];     // raw xl tile (PV operand)
    __shared__ float pl[4 * 64 * 4];  // per-wave p transpose [w][j][4i]
    __shared__ float xr_s[16 * 64];   // this block's 16 xr rows (scaled)
    __shared__ float sa_s[64];

    const int ib = blockIdx.x;        // 0..31 (16 i-rows each)
    const int inst = blockIdx.y;      // 0..15
    const int br = inst >> 3;
    const int tid = threadIdx.x, w = tid >> 6, lane = tid & 63;
    const float* SXL = ws + OFF_SXL + (size_t)inst * NN * 64;
    const float* SXR = ws + OFF_SXR + (size_t)inst * NN * 64;
    const float* XLR = ws + OFF_XLR + (size_t)inst * NN * 64;
    const float* UU  = ws + OFF_UU + inst * NN;
    const float* VV  = ws + OFF_VV + inst * NN;
    const float* SA  = ws + OFF_SA + br * 64;
    const float* bias = br ? b1 : b0;
    const int r0 = ib * 16 + w * 4;

    {   // stage this block's xr rows + sa (one time)
        const float4* s4 = (const float4*)(SXR + (size_t)ib * 16 * 64);
        ((float4*)xr_s)[tid] = s4[tid];
        if (tid < 16) ((float4*)sa_s)[tid] = ((const float4*)SA)[tid];
    }

    float m[4], l[4], oa[4], ob[4], sc[4], uu[4];
#pragma unroll
    for (int i = 0; i < 4; ++i) { m[i] = -1e30f; l[i] = 0.f; oa[i] = 0.f; ob[i] = 0.f; }
#pragma unroll
    for (int i = 0; i < 4; ++i) uu[i] = UU[r0 + i];

    for (int t = 0; t < 8; ++t) {
        __syncthreads();   // protect xt/pl from previous iteration readers
        {   // stage raw-xl tile (16 KB, contiguous)
            const float4* s4 = (const float4*)(XLR + (size_t)t * 64 * 64);
            float4* d4 = (float4*)xt;
#pragma unroll
            for (int k2 = 0; k2 < 4; ++k2) d4[k2 * 256 + tid] = s4[k2 * 256 + tid];
        }
        __syncthreads();

        // per-lane scaled-xl row (lane = j within tile) -> 64 VGPRs
        float xlv[64];
        {
            const float4* s4 = (const float4*)(SXL + (size_t)(t * 64 + lane) * 64);
#pragma unroll
            for (int q = 0; q < 16; ++q) {
                float4 v = s4[q];
                xlv[4 * q + 0] = v.x; xlv[4 * q + 1] = v.y;
                xlv[4 * q + 2] = v.z; xlv[4 * q + 3] = v.w;
            }
        }
        float vj = VV[t * 64 + lane];

#pragma unroll
        for (int ii = 0; ii < 4; ++ii) {
            const float4* xr4 = (const float4*)(xr_s + (w * 4 + ii) * 64);
            const float4* sa4 = (const float4*)sa_s;
            float a0c = 0.f, a1c = 0.f, a2c = 0.f, a3c = 0.f;
#pragma unroll
            for (int q = 0; q < 16; ++q) {
                float4 xq = xr4[q];   // wave-uniform LDS broadcast
                float4 sq = sa4[q];   // wave-uniform LDS broadcast
                a0c = fmaf(sq.x, fabsf(xq.x + xlv[4 * q + 0]), a0c);
                a1c = fmaf(sq.y, fabsf(xq.y + xlv[4 * q + 1]), a1c);
                a2c = fmaf(sq.z, fabsf(xq.z + xlv[4 * q + 2]), a2c);
                a3c = fmaf(sq.w, fabsf(xq.w + xlv[4 * q + 3]), a3c);
            }
            float e = uu[ii] + vj + ((a0c + a1c) + (a2c + a3c));
            float tm = e;
#pragma unroll
            for (int mm = 32; mm > 0; mm >>= 1) tm = fmaxf(tm, __shfl_xor(tm, mm, 64));
            float mn = fmaxf(m[ii], tm);
            float scale = __expf(m[ii] - mn);
            float p = __expf(e - mn);
            float ps = p;
#pragma unroll
            for (int mm = 32; mm > 0; mm >>= 1) ps += __shfl_xor(ps, mm, 64);
            l[ii] = l[ii] * scale + ps;
            m[ii] = mn; sc[ii] = scale;
            pl[(w * 64 + lane) * 4 + ii] = p;
        }

        // ---- PV: out[i, d=lane] += sum_j p_ij * xl[j, d] ----
#pragma unroll
        for (int ii = 0; ii < 4; ++ii) { oa[ii] *= sc[ii]; ob[ii] *= sc[ii]; }
        const float4* p4 = (const float4*)pl;
        for (int jj = 0; jj < 64; jj += 2) {
            float4 pv0 = p4[w * 64 + jj];         // broadcast b128
            float4 pv1 = p4[w * 64 + jj + 1];
            float xv0 = xt[jj * 64 + lane];       // 2-way alias (free)
            float xv1 = xt[(jj + 1) * 64 + lane];
            oa[0] = fmaf(pv0.x, xv0, oa[0]); ob[0] = fmaf(pv1.x, xv1, ob[0]);
            oa[1] = fmaf(pv0.y, xv0, oa[1]); ob[1] = fmaf(pv1.y, xv1, ob[1]);
            oa[2] = fmaf(pv0.z, xv0, oa[2]); ob[2] = fmaf(pv1.z, xv1, ob[2]);
            oa[3] = fmaf(pv0.w, xv0, oa[3]); ob[3] = fmaf(pv1.w, xv1, ob[3]);
        }
    }

    float bv = bias[lane];
#pragma unroll
    for (int ii = 0; ii < 4; ++ii) {
        float vsum = (oa[ii] + ob[ii]) / l[ii] + bv;
        float th = 1.f - 2.f / (__expf(2.f * vsum) + 1.f);   // tanh
        Hout[(size_t)(inst * NN + r0 + ii) * 64 + lane] = th;
    }
}

// ---------------- mean-pool over nodes ----------------
__global__ __launch_bounds__(256) void kpool(const float* __restrict__ H2, float* __restrict__ out)
{
    __shared__ float red[4][64];
    const int inst = blockIdx.x;
    const int tid = threadIdx.x, ig = tid >> 6, lane = tid & 63;
    float s = 0.f;
    for (int i = ig; i < NN; i += 4) s += H2[(size_t)(inst * NN + i) * 64 + lane];
    red[ig][lane] = s;
    __syncthreads();
    if (tid < 64) {
        float v = (red[0][tid] + red[1][tid] + red[2][tid] + red[3][tid]) * (1.f / NN);
        out[inst * 64 + tid] = v;   // inst = br*8+b -> br*512 + b*64 + d
    }
}

extern "C" void kernel_launch(void* const* d_in, const int* in_sizes, int n_in,
                              void* d_out, int out_size, void* d_ws, size_t ws_size,
                              hipStream_t stream)
{
    (void)in_sizes; (void)n_in; (void)out_size; (void)ws_size;
    const float* feat  = (const float*)d_in[0];
    const float* p1_Wl = (const float*)d_in[1],  *p1_Wr = (const float*)d_in[2];
    const float* p1_a  = (const float*)d_in[3],  *p1_b  = (const float*)d_in[4];
    const float* p2_Wl = (const float*)d_in[5],  *p2_Wr = (const float*)d_in[6];
    const float* p2_a  = (const float*)d_in[7],  *p2_b  = (const float*)d_in[8];
    const float* v1_Wl = (const float*)d_in[9],  *v1_Wr = (const float*)d_in[10];
    const float* v1_a  = (const float*)d_in[11], *v1_b  = (const float*)d_in[12];
    const float* v2_Wl = (const float*)d_in[13], *v2_Wr = (const float*)d_in[14];
    const float* v2_a  = (const float*)d_in[15], *v2_b  = (const float*)d_in[16];

    float* ws = (float*)d_ws;
    float* H1 = ws + OFF_H1;
    float* H2 = ws + OFF_H2;
    float* out = (float*)d_out;

    // layer 1 (input: features, K=128)
    kpre<128><<<dim3(16, 16), 256, 0, stream>>>(feat, 0, p1_Wl, p1_Wr, p1_a,
                                                v1_Wl, v1_Wr, v1_a, ws);
    kattn<<<dim3(32, 16), 256, 0, stream>>>(ws, p1_b, v1_b, H1);
    // layer 2 (input: H1, K=64)
    kpre<64><<<dim3(16, 16), 256, 0, stream>>>(H1, 1, p2_Wl, p2_Wr, p2_a,
                                               v2_Wl, v2_Wr, v2_a, ws);
    kattn<<<dim3(32, 16), 256, 0, stream>>>(ws, p2_b, v2_b, H2);
    // pool
    kpool<<<16, 256, 0, stream>>>(H2, out);
}

// Round 2
// 139.445 us; speedup vs baseline: 2.3851x; 2.3851x over previous
//
#include <hip/hip_runtime.h>
#include <math.h>

#define NN 512
// ws layout (float offsets)
#define OFF_XL 0u
#define OFF_XR 524288u
#define OFF_UU 1048576u
#define OFF_VV 1056768u
#define OFF_SA 1064960u
#define OFF_H1 1065088u
#define OFF_H2 1589376u

// ---------------- GEMM + u/v/sa precompute (raw xl, xr only) ----------------
template<int K>
__global__ __launch_bounds__(256) void kpre(
    const float* __restrict__ src, int srcPerInst,
    const float* __restrict__ Wl0, const float* __restrict__ Wr0, const float* __restrict__ a0,
    const float* __restrict__ Wl1, const float* __restrict__ Wr1, const float* __restrict__ a1,
    float* __restrict__ ws)
{
    __shared__ float xs[16 * K];
    __shared__ float wbuf[2][32 * 64];   // staged Wl/Wr chunk (32 k x 64 d each)
    const int rb   = blockIdx.x;   // 0..31 : 16-row block
    const int inst = blockIdx.y;   // 0..15 (br*8 + batch)
    const int br   = inst >> 3;
    const int tid  = threadIdx.x;
    const int d = tid & 63, ig = tid >> 6;
    const float* Wl = br ? Wl1 : Wl0;
    const float* Wr = br ? Wr1 : Wr0;
    const float* av = br ? a1  : a0;
    const float* sp = src + (size_t)(srcPerInst ? inst : (inst & 7)) * NN * K + (size_t)rb * 16 * K;

    {   // stage 16 rows x K floats (contiguous)
        const float4* s4 = (const float4*)sp;
        float4* d4 = (float4*)xs;
        const int tot = 16 * K / 4;
        for (int i = tid; i < tot; i += 256) d4[i] = s4[i];
    }

    float accl[4] = {0.f,0.f,0.f,0.f}, accr[4] = {0.f,0.f,0.f,0.f};
    const int NC = K / 32;
    for (int kc = 0; kc < NC; ++kc) {
        __syncthreads();   // prev chunk readers done (also covers xs stage at kc=0)
        {   // stage W chunk: 32 k x 64 d x 2 matrices = 16 KB
            const float4* wl4 = (const float4*)(Wl + kc * 32 * 64);
            const float4* wr4 = (const float4*)(Wr + kc * 32 * 64);
            float4* b0 = (float4*)wbuf[0];
            float4* b1 = (float4*)wbuf[1];
            b0[tid] = wl4[tid]; b0[tid + 256] = wl4[tid + 256];
            b1[tid] = wr4[tid]; b1[tid + 256] = wr4[tid + 256];
        }
        __syncthreads();
#pragma unroll
        for (int k4 = 0; k4 < 8; ++k4) {   // 4 k per step
            float xc[4][4];
#pragma unroll
            for (int rr = 0; rr < 4; ++rr) {
                float4 xv = ((const float4*)xs)[(ig * 4 + rr) * (K / 4) + kc * 8 + k4];
                xc[rr][0] = xv.x; xc[rr][1] = xv.y; xc[rr][2] = xv.z; xc[rr][3] = xv.w;
            }
#pragma unroll
            for (int ee = 0; ee < 4; ++ee) {
                float wl = wbuf[0][(k4 * 4 + ee) * 64 + d];   // lanes consecutive: conflict-free
                float wr = wbuf[1][(k4 * 4 + ee) * 64 + d];
#pragma unroll
                for (int rr = 0; rr < 4; ++rr) {
                    accl[rr] = fmaf(xc[rr][ee], wl, accl[rr]);
                    accr[rr] = fmaf(xc[rr][ee], wr, accr[rr]);
                }
            }
        }
    }

    float aval = av[d];
    float* XL = ws + OFF_XL; float* XR = ws + OFF_XR;
    float* UU = ws + OFF_UU; float* VV = ws + OFF_VV; float* SA = ws + OFF_SA;
#pragma unroll
    for (int rr = 0; rr < 4; ++rr) {
        int row = rb * 16 + ig * 4 + rr;
        size_t o = (size_t)(inst * NN + row) * 64 + d;
        XL[o] = accl[rr];
        XR[o] = accr[rr];
        float pu = aval * accr[rr];   // -> u_i (query side, from xr)
        float pv = aval * accl[rr];   // -> v_j (source side, from xl)
#pragma unroll
        for (int mm = 32; mm > 0; mm >>= 1) {
            pu += __shfl_xor(pu, mm, 64);
            pv += __shfl_xor(pv, mm, 64);
        }
        if (d == 0) { UU[inst * NN + row] = 0.6f * pu; VV[inst * NN + row] = 0.6f * pv; }
    }
    if (rb == 0 && ig == 0 && (inst & 7) == 0) SA[br * 64 + d] = 0.4f * aval;
}

// ------- fused attention: two-phase softmax, swizzled double-buffered xl tile -------
__global__ __launch_bounds__(256) void kattn(
    const float* __restrict__ ws,
    const float* __restrict__ b0, const float* __restrict__ b1,
    float* __restrict__ Hout)
{
    __shared__ float xt[2][64 * 64];    // swizzled xl tile, double-buffered (32 KB)
    __shared__ float xr_s[16 * 64];     // this block's 16 xr rows
    __shared__ float4 pl[4][64];        // per-wave p transpose [w][j] -> 4 i
    __shared__ float sa_s[64];

    const int ib   = blockIdx.x;        // 0..31 : 16 i-rows per block
    const int inst = blockIdx.y;        // 0..15
    const int br   = inst >> 3;
    const int tid = threadIdx.x, w = tid >> 6, lane = tid & 63;
    const float* XL = ws + OFF_XL + (size_t)inst * NN * 64;
    const float* XR = ws + OFF_XR + (size_t)inst * NN * 64;
    const float* UU = ws + OFF_UU + inst * NN;
    const float* VV = ws + OFF_VV + inst * NN;
    const float* SA = ws + OFF_SA + br * 64;
    const float* bias = br ? b1 : b0;
    const int r0 = ib * 16 + w * 4;
    const float4* XL4 = (const float4*)XL;

    {   // one-time staging (consumed after first barrier)
        ((float4*)xr_s)[tid] = ((const float4*)XR)[ib * 256 + tid];
        if (tid < 16) ((float4*)sa_s)[tid] = ((const float4*)SA)[tid];
    }

    float uu[4];
#pragma unroll
    for (int ii = 0; ii < 4; ++ii) uu[ii] = UU[r0 + ii];

    float e[8][4];     // scores (later: unnormalized p)
    float4 g[4];       // staging registers (issue-early / write-late)

    // prologue: load tile 0 (linear, fully coalesced)
#pragma unroll
    for (int r = 0; r < 4; ++r) g[r] = XL4[r * 256 + tid];

    // ---------------- Phase A: all scores ----------------
#pragma unroll
    for (int t = 0; t < 8; ++t) {
        const int buf = t & 1;
#pragma unroll
        for (int r = 0; r < 4; ++r) {   // swizzled LDS write
            int ld = r * 256 + tid;     // float4 slot 0..1023
            int j = ld >> 4, s = ld & 15;
            ((float4*)xt[buf])[j * 16 + (s ^ (j & 15))] = g[r];
        }
        if (t < 7) {
#pragma unroll
            for (int r = 0; r < 4; ++r) g[r] = XL4[(t + 1) * 1024 + r * 256 + tid];
        }
        float vj = VV[t * 64 + lane];
        __syncthreads();

        float c0[4], c1[4], c2[4], c3[4];
#pragma unroll
        for (int ii = 0; ii < 4; ++ii) { c0[ii]=0.f; c1[ii]=0.f; c2[ii]=0.f; c3[ii]=0.f; }
        const float4* xrow = (const float4*)xt[buf] + lane * 16;   // lane's j-row
#pragma unroll
        for (int q = 0; q < 16; ++q) {
            float4 x4 = xrow[q ^ (lane & 15)];            // swizzled row read (data-floor)
            float4 s4 = ((const float4*)sa_s)[q];         // broadcast
#pragma unroll
            for (int ii = 0; ii < 4; ++ii) {
                float4 r4 = ((const float4*)xr_s)[(w * 4 + ii) * 16 + q];   // broadcast
                c0[ii] = fmaf(s4.x, fabsf(r4.x + x4.x), c0[ii]);
                c1[ii] = fmaf(s4.y, fabsf(r4.y + x4.y), c1[ii]);
                c2[ii] = fmaf(s4.z, fabsf(r4.z + x4.z), c2[ii]);
                c3[ii] = fmaf(s4.w, fabsf(r4.w + x4.w), c3[ii]);
            }
        }
#pragma unroll
        for (int ii = 0; ii < 4; ++ii)
            e[t][ii] = uu[ii] + vj + ((c0[ii] + c1[ii]) + (c2[ii] + c3[ii]));
    }

    // prefetch PV tile 0 before the softmax reduction (hide VMEM latency under Phase B)
#pragma unroll
    for (int r = 0; r < 4; ++r) g[r] = XL4[r * 256 + tid];

    // ---------------- Phase B: one softmax reduction per row ----------------
    float l[4];
#pragma unroll
    for (int ii = 0; ii < 4; ++ii) {
        float mx = e[0][ii];
#pragma unroll
        for (int t = 1; t < 8; ++t) mx = fmaxf(mx, e[t][ii]);
#pragma unroll
        for (int mm = 32; mm > 0; mm >>= 1) mx = fmaxf(mx, __shfl_xor(mx, mm, 64));
        float ssum = 0.f;
#pragma unroll
        for (int t = 0; t < 8; ++t) { e[t][ii] = __expf(e[t][ii] - mx); ssum += e[t][ii]; }
#pragma unroll
        for (int mm = 32; mm > 0; mm >>= 1) ssum += __shfl_xor(ssum, mm, 64);
        l[ii] = ssum;
    }

    // ---------------- Phase C: PV ----------------
    float oa[4] = {0.f,0.f,0.f,0.f};
#pragma unroll
    for (int t = 0; t < 8; ++t) {
        const int buf = t & 1;
#pragma unroll
        for (int r = 0; r < 4; ++r) {
            int ld = r * 256 + tid;
            int j = ld >> 4, s = ld & 15;
            ((float4*)xt[buf])[j * 16 + (s ^ (j & 15))] = g[r];
        }
        if (t < 7) {
#pragma unroll
            for (int r = 0; r < 4; ++r) g[r] = XL4[(t + 1) * 1024 + r * 256 + tid];
        }
        pl[w][lane] = make_float4(e[t][0], e[t][1], e[t][2], e[t][3]);   // own-wave region
        __syncthreads();

        const float* xb = xt[buf];
#pragma unroll 8
        for (int jj = 0; jj < 64; ++jj) {
            float4 pv = pl[w][jj];   // broadcast
            // column read through the swizzle: (row jj, d=lane) -> 2-way alias, free
            float xv = xb[jj * 64 + 4 * ((lane >> 2) ^ (jj & 15)) + (lane & 3)];
            oa[0] = fmaf(pv.x, xv, oa[0]);
            oa[1] = fmaf(pv.y, xv, oa[1]);
            oa[2] = fmaf(pv.z, xv, oa[2]);
            oa[3] = fmaf(pv.w, xv, oa[3]);
        }
    }

    float bv = bias[lane];
#pragma unroll
    for (int ii = 0; ii < 4; ++ii) {
        float v = oa[ii] / l[ii] + bv;
        float th = 1.f - 2.f / (__expf(2.f * v) + 1.f);   // tanh
        Hout[(size_t)(inst * NN + r0 + ii) * 64 + lane] = th;
    }
}

// ---------------- mean-pool over nodes ----------------
__global__ __launch_bounds__(1024) void kpool(const float* __restrict__ H2, float* __restrict__ out)
{
    __shared__ float red[16][64];
    const int inst = blockIdx.x;
    const int tid = threadIdx.x, ig = tid >> 6, lane = tid & 63;
    float s = 0.f;
    for (int i = ig; i < NN; i += 16) s += H2[(size_t)(inst * NN + i) * 64 + lane];
    red[ig][lane] = s;
    __syncthreads();
    if (tid < 64) {
        float v = 0.f;
#pragma unroll
        for (int k = 0; k < 16; ++k) v += red[k][tid];
        out[inst * 64 + tid] = v * (1.f / NN);
    }
}

extern "C" void kernel_launch(void* const* d_in, const int* in_sizes, int n_in,
                              void* d_out, int out_size, void* d_ws, size_t ws_size,
                              hipStream_t stream)
{
    (void)in_sizes; (void)n_in; (void)out_size; (void)ws_size;
    const float* feat  = (const float*)d_in[0];
    const float* p1_Wl = (const float*)d_in[1],  *p1_Wr = (const float*)d_in[2];
    const float* p1_a  = (const float*)d_in[3],  *p1_b  = (const float*)d_in[4];
    const float* p2_Wl = (const float*)d_in[5],  *p2_Wr = (const float*)d_in[6];
    const float* p2_a  = (const float*)d_in[7],  *p2_b  = (const float*)d_in[8];
    const float* v1_Wl = (const float*)d_in[9],  *v1_Wr = (const float*)d_in[10];
    const float* v1_a  = (const float*)d_in[11], *v1_b  = (const float*)d_in[12];
    const float* v2_Wl = (const float*)d_in[13], *v2_Wr = (const float*)d_in[14];
    const float* v2_a  = (const float*)d_in[15], *v2_b  = (const float*)d_in[16];

    float* ws = (float*)d_ws;
    float* H1 = ws + OFF_H1;
    float* H2 = ws + OFF_H2;
    float* out = (float*)d_out;

    // layer 1 (input: features, K=128)
    kpre<128><<<dim3(32, 16), 256, 0, stream>>>(feat, 0, p1_Wl, p1_Wr, p1_a,
                                                v1_Wl, v1_Wr, v1_a, ws);
    kattn<<<dim3(32, 16), 256, 0, stream>>>(ws, p1_b, v1_b, H1);
    // layer 2 (input: H1, K=64)
    kpre<64><<<dim3(32, 16), 256, 0, stream>>>(H1, 1, p2_Wl, p2_Wr, p2_a,
                                               v2_Wl, v2_Wr, v2_a, ws);
    kattn<<<dim3(32, 16), 256, 0, stream>>>(ws, p2_b, v2_b, H2);
    // pool
    kpool<<<16, 1024, 0, stream>>>(H2, out);
}